// Round 7
// baseline (711.571 us; speedup 1.0000x reference)
//
#include <hip/hip_runtime.h>
#include <cstdint>
#include <cstddef>

typedef __attribute__((ext_vector_type(8))) _Float16 half8;
typedef __attribute__((ext_vector_type(4))) _Float16 half4;
typedef __attribute__((ext_vector_type(4))) float f32x4;

#define DEV static __device__ __forceinline__
#define AS1(p) (const __attribute__((address_space(1))) void*)(p)
#define AS3(p) (__attribute__((address_space(3))) void*)(p)

DEV half8 cvt8(const float* p) {
    f32x4 a = *(const f32x4*)p;
    f32x4 b = *(const f32x4*)(p + 4);
    half8 o;
    o[0] = (_Float16)a[0]; o[1] = (_Float16)a[1];
    o[2] = (_Float16)a[2]; o[3] = (_Float16)a[3];
    o[4] = (_Float16)b[0]; o[5] = (_Float16)b[1];
    o[6] = (_Float16)b[2]; o[7] = (_Float16)b[3];
    return o;
}

// ---- elementwise f32 -> f16 ----
__global__ __launch_bounds__(256)
void cvt_kernel(const float* __restrict__ in, _Float16* __restrict__ out, int n8)
{
    int i = blockIdx.x * 256 + threadIdx.x;
    int stride = gridDim.x * 256;
    for (; i < n8; i += stride)
        ((half8*)out)[i] = cvt8(in + (size_t)i * 8);
}

// ---- elementwise f16+f16 -> f16 (in-place safe) ----
__global__ __launch_bounds__(256)
void opsum_kernel(const _Float16* __restrict__ a, const _Float16* __restrict__ b,
                  _Float16* __restrict__ out, int n8)
{
    int i = blockIdx.x * 256 + threadIdx.x;
    int stride = gridDim.x * 256;
    for (; i < n8; i += stride) {
        half8 x = ((const half8*)a)[i];
        half8 y = ((const half8*)b)[i];
        half8 o;
#pragma unroll
        for (int j = 0; j < 8; j++) o[j] = (_Float16)((float)x[j] + (float)y[j]);
        ((half8*)out)[i] = o;
    }
}

// ---- combine: attn_mean = (p0 + p1) / 16, f16 partials -> f32 ----
__global__ __launch_bounds__(256)
void combine_kernel(const _Float16* __restrict__ a, const _Float16* __restrict__ b,
                    float* __restrict__ out, int n8)
{
    int i = blockIdx.x * 256 + threadIdx.x;
    int stride = gridDim.x * 256;
    for (; i < n8; i += stride) {
        half8 x = ((const half8*)a)[i];
        half8 y = ((const half8*)b)[i];
        f32x4 o0, o1;
#pragma unroll
        for (int j = 0; j < 4; j++) o0[j] = ((float)x[j] + (float)y[j]) * 0.0625f;
#pragma unroll
        for (int j = 0; j < 4; j++) o1[j] = ((float)x[j + 4] + (float)y[j + 4]) * 0.0625f;
        *(f32x4*)(out + (size_t)i * 8) = o0;
        *(f32x4*)(out + (size_t)i * 8 + 4) = o1;
    }
}

// ---- f16 GEMM with global_load_lds staging ----
template<bool OUT_F16>
__global__ __launch_bounds__(256, 2)
void gemm16(const _Float16* __restrict__ A, const _Float16* __restrict__ B,
            const float* __restrict__ bias, float scale, void* __restrict__ Cout,
            int M, int N, int K)
{
    __shared__ half8 As[2][512];
    __shared__ half8 Bs[2][512];
    const int tid = threadIdx.x, l = tid & 63, w = tid >> 6;
    const int lr = l & 15, lh = l >> 4;
    const int wm0 = (w >> 1) * 64, wn0 = (w & 1) * 64;
    const int bm0 = blockIdx.x * 128, bn0 = blockIdx.y * 128;
    const int nsteps = K >> 5;

    f32x4 acc[4][4] = {};

#define STAGE(buf, t) do {                                                        \
        int k0 = (t) << 5;                                                        \
        _Pragma("unroll")                                                         \
        for (int q2 = 0; q2 < 2; q2++) {                                          \
            int r = q2 * 64 + l;                                                  \
            __builtin_amdgcn_global_load_lds(                                     \
                AS1(A + (size_t)(bm0 + r) * K + k0 + w * 8),                      \
                AS3(&As[buf][w * 128 + q2 * 64]), 16, 0, 0);                      \
            __builtin_amdgcn_global_load_lds(                                     \
                AS1(B + (size_t)(bn0 + r) * K + k0 + w * 8),                      \
                AS3(&Bs[buf][w * 128 + q2 * 64]), 16, 0, 0);                      \
        }                                                                         \
    } while (0)

    STAGE(0, 0);
    __syncthreads();
    for (int t = 0; t < nsteps; t++) {
        int cur = t & 1;
        if (t + 1 < nsteps) STAGE(cur ^ 1, t + 1);
        half8 a[4], b[4];
#pragma unroll
        for (int m = 0; m < 4; m++) a[m] = As[cur][lh * 128 + wm0 + m * 16 + lr];
#pragma unroll
        for (int n = 0; n < 4; n++) b[n] = Bs[cur][lh * 128 + wn0 + n * 16 + lr];
#pragma unroll
        for (int m = 0; m < 4; m++)
#pragma unroll
            for (int n = 0; n < 4; n++)
                acc[m][n] = __builtin_amdgcn_mfma_f32_16x16x32_f16(a[m], b[n], acc[m][n], 0, 0, 0);
        __syncthreads();
    }
#undef STAGE

#pragma unroll
    for (int m = 0; m < 4; m++)
#pragma unroll
        for (int n = 0; n < 4; n++) {
            int row0 = bm0 + wm0 + m * 16 + lh * 4;
            int col = bn0 + wn0 + n * 16 + lr;
            float bv = bias[col];
#pragma unroll
            for (int j = 0; j < 4; j++) {
                float val = (acc[m][n][j] + bv) * scale;
                int row = row0 + j;
                if constexpr (OUT_F16)
                    ((_Float16*)Cout)[(size_t)row * N + col] = (_Float16)val;
                else
                    ((float*)Cout)[(size_t)row * N + col] = val;
            }
        }
}

// ---- legacy GEMM (f32 inputs) -- V projection, writes VT[b][dv][t] ----
template<int BM, int BN, int WR, int WC>
__global__ __launch_bounds__(256, 2)
void gemm_vp(const float* __restrict__ Aptr, const float* __restrict__ Bw,
             const float* __restrict__ bias, _Float16* __restrict__ Cout, int M, int N, int K)
{
    constexpr int BK = 32;
    constexpr int WM = BM / WR, WN = BN / WC;
    constexpr int MF = WM / 16, NF = WN / 16;
    constexpr int LDT = 40;
    __shared__ _Float16 Asl[BM][LDT];
    __shared__ _Float16 Bsl[BN][LDT];

    const int tid = threadIdx.x;
    const int l = tid & 63;
    const int w = tid >> 6;
    const int wr = w / WC, wc = w % WC;
    const int lr = l & 15, lh = l >> 4;
    const int bm0 = blockIdx.y * BM, bn0 = blockIdx.x * BN;

    f32x4 acc[MF][NF] = {};

    for (int k0 = 0; k0 < K; k0 += BK) {
        __syncthreads();
        for (int c = tid; c < BM * 4; c += 256) {
            int row = c >> 2, c8 = (c & 3) << 3;
            *(half8*)&Asl[row][c8] = cvt8(Aptr + (size_t)(bm0 + row) * K + k0 + c8);
        }
        for (int c = tid; c < BN * 4; c += 256) {
            int row = c >> 2, c8 = (c & 3) << 3;
            *(half8*)&Bsl[row][c8] = cvt8(Bw + (size_t)(bn0 + row) * K + k0 + c8);
        }
        __syncthreads();

        half8 a[MF], b[NF];
#pragma unroll
        for (int m = 0; m < MF; m++)
            a[m] = *(const half8*)&Asl[wr * WM + m * 16 + lr][lh * 8];
#pragma unroll
        for (int n = 0; n < NF; n++)
            b[n] = *(const half8*)&Bsl[wc * WN + n * 16 + lr][lh * 8];
#pragma unroll
        for (int m = 0; m < MF; m++)
#pragma unroll
            for (int n = 0; n < NF; n++)
                acc[m][n] = __builtin_amdgcn_mfma_f32_16x16x32_f16(a[m], b[n], acc[m][n], 0, 0, 0);
    }

#pragma unroll
    for (int m = 0; m < MF; m++)
#pragma unroll
        for (int n = 0; n < NF; n++) {
            int row0 = bm0 + wr * WM + m * 16 + lh * 4;
            int col = bn0 + wc * WN + n * 16 + lr;
            float bv = bias[col];
#pragma unroll
            for (int j = 0; j < 4; j++) {
                float val = acc[m][n][j] + bv;
                int row = row0 + j;
                int bi = row >> 11, t = row & 2047;
                Cout[(((size_t)(bi * 64 + col)) << 11) + t] = (_Float16)val;
            }
        }
}

// ---- Fused attention v2: 1 head per wave -> ~112 unified regs -> 2 blocks/CU ----
// Grid 1024 = 4b x 2ks x 2hg x 64 q-tiles. Block: 8 waves = 8 heads (hg half).
// blk%8=(b,ks) pins a 2MB K-half per XCD L2 (phase 2); head-groups read disjoint
// column halves so K traffic is unchanged vs R6.
// Phase 1: full-K denominators (redundant across ks pair). Phase 2: own k-half,
// p -> 8-head f16 partial (combine kernel finishes the 16-head mean), PV -> O partial.
__global__ __launch_bounds__(512, 4)
void attn2_kernel(const _Float16* __restrict__ Qh, const _Float16* __restrict__ Kh,
                  const _Float16* __restrict__ VT, _Float16* __restrict__ attnp,
                  _Float16* __restrict__ Op)
{
    const int blk = blockIdx.x;
    const int b = blk & 3;
    const int ks = (blk >> 2) & 1;
    const int hg = (blk >> 3) & 1;
    const int q0 = (blk >> 4) << 5;
    const int tid = threadIdx.x;
    const int l = tid & 63, w = tid >> 6;
    const int lr = l & 15, lh = l >> 4;
    const int ch = (hg * 8 + w) * 64;   // this wave's head column base

    __shared__ float pw[8][32][34];
    __shared__ _Float16 Pld[8][32][44];

    const size_t base = (size_t)b * 2048 * 1024;
    const _Float16* Qb = Qh + base;
    const _Float16* Kb = Kh + base;

    // Q fragments: [mfrag][dk]
    half8 qf[2][2];
#pragma unroll
    for (int m = 0; m < 2; m++)
#pragma unroll
        for (int dk = 0; dk < 2; dk++)
            qf[m][dk] = *(const half8*)(Qb + (size_t)(q0 + m * 16 + lr) * 1024
                                        + ch + dk * 32 + lh * 8);

    // ---- Phase 1: full-K denominators ----
    float sl[2][4] = {};
    for (int kt = 0; kt < 64; kt++) {
        const _Float16* kp = Kb + (size_t)(kt * 32) * 1024;
        half8 kfh[2][2];
#pragma unroll
        for (int kfr = 0; kfr < 2; kfr++)
#pragma unroll
            for (int dk = 0; dk < 2; dk++)
                kfh[kfr][dk] = *(const half8*)(kp + (size_t)(kfr * 16 + lr) * 1024
                                               + ch + dk * 32 + lh * 8);
        f32x4 sc[2][2] = {};
#pragma unroll
        for (int m = 0; m < 2; m++)
#pragma unroll
            for (int kfr = 0; kfr < 2; kfr++)
#pragma unroll
                for (int dk = 0; dk < 2; dk++)
                    sc[m][kfr] = __builtin_amdgcn_mfma_f32_16x16x32_f16(
                        qf[m][dk], kfh[kfr][dk], sc[m][kfr], 0, 0, 0);
#pragma unroll
        for (int m = 0; m < 2; m++)
#pragma unroll
            for (int j = 0; j < 4; j++)
                sl[m][j] += __builtin_amdgcn_exp2f(sc[m][0][j])
                          + __builtin_amdgcn_exp2f(sc[m][1][j]);
    }
    float rinv[2][4];
#pragma unroll
    for (int m = 0; m < 2; m++)
#pragma unroll
        for (int j = 0; j < 4; j++) {
            float s = sl[m][j];
#pragma unroll
            for (int d = 1; d < 16; d <<= 1)
                s += __shfl_xor(s, d, 64);
            rinv[m][j] = 1.0f / s;
        }

    // ---- Phase 2: emit own k-half ----
    f32x4 oacc[2][4] = {};
    __syncthreads();

    const int kt0 = ks * 32, kt1 = kt0 + 32;
    for (int kt = kt0; kt < kt1; kt++) {
        const int krow = kt * 32;
        const _Float16* kp = Kb + (size_t)krow * 1024;
        half8 kfh[2][2];
#pragma unroll
        for (int kfr = 0; kfr < 2; kfr++)
#pragma unroll
            for (int dk = 0; dk < 2; dk++)
                kfh[kfr][dk] = *(const half8*)(kp + (size_t)(kfr * 16 + lr) * 1024
                                               + ch + dk * 32 + lh * 8);
        f32x4 sc[2][2] = {};
#pragma unroll
        for (int m = 0; m < 2; m++)
#pragma unroll
            for (int kfr = 0; kfr < 2; kfr++)
#pragma unroll
                for (int dk = 0; dk < 2; dk++)
                    sc[m][kfr] = __builtin_amdgcn_mfma_f32_16x16x32_f16(
                        qf[m][dk], kfh[kfr][dk], sc[m][kfr], 0, 0, 0);
        // p, psum -> pw early (frees psum before PV), Pld stash for transpose
#pragma unroll
        for (int m = 0; m < 2; m++)
#pragma unroll
            for (int kfr = 0; kfr < 2; kfr++) {
#pragma unroll
                for (int j = 0; j < 4; j++) {
                    float p = __builtin_amdgcn_exp2f(sc[m][kfr][j]) * rinv[m][j];
                    Pld[w][m * 16 + lh * 4 + j][kfr * 16 + lr] = (_Float16)p;
                    pw[w][m * 16 + lh * 4 + j][kfr * 16 + lr] = p;
                }
            }
        // V frags + P transpose reads (wave-local, before barrier)
        half8 vf[4];
#pragma unroll
        for (int dv = 0; dv < 4; dv++)
            vf[dv] = *(const half8*)(VT + (((size_t)(b * 64 + dv * 16 + lr)) << 11) + krow + lh * 8);
        half8 pa[2];
#pragma unroll
        for (int m = 0; m < 2; m++) {
            union { half8 v8; half4 v4[2]; } pu;
            pu.v4[0] = *(const half4*)&Pld[w][m * 16 + lr][lh * 8];
            pu.v4[1] = *(const half4*)&Pld[w][m * 16 + lr][lh * 8 + 4];
            pa[m] = pu.v8;
        }
        __syncthreads();
        // PV MFMA co-schedules with other waves' LDS reduce
#pragma unroll
        for (int m = 0; m < 2; m++)
#pragma unroll
            for (int dv = 0; dv < 4; dv++)
                oacc[m][dv] = __builtin_amdgcn_mfma_f32_16x16x32_f16(
                    pa[m], vf[dv], oacc[m][dv], 0, 0, 0);
        // 8-head partial sum -> f16
        for (int idx = tid; idx < 1024; idx += 512) {
            int r = idx >> 5, c = idx & 31;
            float s = 0.f;
#pragma unroll
            for (int ww = 0; ww < 8; ww++) s += pw[ww][r][c];
            attnp[(size_t)hg * 16777216 + (((size_t)(b * 2048 + q0 + r)) << 11) + krow + c]
                = (_Float16)s;
        }
        __syncthreads();
    }

    // O partial for this k-half (f16), disjoint column halves per hg
    _Float16* op = Op + (size_t)ks * 8388608 + base;
#pragma unroll
    for (int m = 0; m < 2; m++)
#pragma unroll
        for (int dv = 0; dv < 4; dv++)
#pragma unroll
            for (int j = 0; j < 4; j++) {
                int row = q0 + m * 16 + lh * 4 + j;
                int col = ch + dv * 16 + lr;
                op[(size_t)row * 1024 + col] = (_Float16)oacc[m][dv][j];
            }
}

// ---- R6 fallback (2 heads/wave, f32 attn_out direct) for small workspaces ----
__global__ __launch_bounds__(512, 2)
void attn_kernel(const _Float16* __restrict__ Qh, const _Float16* __restrict__ Kh,
                 const _Float16* __restrict__ VT, float* __restrict__ attn_out,
                 _Float16* __restrict__ Op)
{
    const int blk = blockIdx.x;
    const int b = blk & 3;
    const int ks = (blk >> 2) & 1;
    const int q0 = (blk >> 3) << 5;
    const int tid = threadIdx.x;
    const int l = tid & 63, w = tid >> 6;
    const int lr = l & 15, lh = l >> 4;
    const int h0 = w << 1;

    __shared__ float pw[8][32][34];
    __shared__ _Float16 Pld[8][32][44];

    const size_t base = (size_t)b * 2048 * 1024;
    const _Float16* Qb = Qh + base;
    const _Float16* Kb = Kh + base;

    half8 qf[2][2][2];
#pragma unroll
    for (int hh = 0; hh < 2; hh++)
#pragma unroll
        for (int m = 0; m < 2; m++)
#pragma unroll
            for (int dk = 0; dk < 2; dk++)
                qf[hh][m][dk] = *(const half8*)(Qb + (size_t)(q0 + m * 16 + lr) * 1024
                                                + (h0 + hh) * 64 + dk * 32 + lh * 8);

    float sl[2][2][4] = {};
    for (int kt = 0; kt < 64; kt++) {
        const _Float16* kp = Kb + (size_t)(kt * 32) * 1024;
#pragma unroll
        for (int hh = 0; hh < 2; hh++) {
            half8 kfh[2][2];
#pragma unroll
            for (int kfr = 0; kfr < 2; kfr++)
#pragma unroll
                for (int dk = 0; dk < 2; dk++)
                    kfh[kfr][dk] = *(const half8*)(kp + (size_t)(kfr * 16 + lr) * 1024
                                                   + (h0 + hh) * 64 + dk * 32 + lh * 8);
#pragma unroll
            for (int m = 0; m < 2; m++) {
                f32x4 sc[2] = {};
#pragma unroll
                for (int kfr = 0; kfr < 2; kfr++)
#pragma unroll
                    for (int dk = 0; dk < 2; dk++)
                        sc[kfr] = __builtin_amdgcn_mfma_f32_16x16x32_f16(
                            qf[hh][m][dk], kfh[kfr][dk], sc[kfr], 0, 0, 0);
#pragma unroll
                for (int j = 0; j < 4; j++)
                    sl[hh][m][j] += __builtin_amdgcn_exp2f(sc[0][j])
                                  + __builtin_amdgcn_exp2f(sc[1][j]);
            }
        }
    }
    float rinv[2][2][4];
#pragma unroll
    for (int hh = 0; hh < 2; hh++)
#pragma unroll
        for (int m = 0; m < 2; m++)
#pragma unroll
            for (int j = 0; j < 4; j++) {
                float s = sl[hh][m][j];
#pragma unroll
                for (int d = 1; d < 16; d <<= 1)
                    s += __shfl_xor(s, d, 64);
                rinv[hh][m][j] = 1.0f / s;
            }

    f32x4 oacc[2][2][4] = {};
    __syncthreads();

    const int kt0 = ks * 32, kt1 = kt0 + 32;
    for (int kt = kt0; kt < kt1; kt++) {
        const int krow = kt * 32;
        const _Float16* kp = Kb + (size_t)krow * 1024;
        half8 vf[4];
#pragma unroll
        for (int dv = 0; dv < 4; dv++)
            vf[dv] = *(const half8*)(VT + (((size_t)(b * 64 + dv * 16 + lr)) << 11) + krow + lh * 8);

        float psum[2][2][4] = {};
#pragma unroll
        for (int hh = 0; hh < 2; hh++) {
            half8 kfh[2][2];
#pragma unroll
            for (int kfr = 0; kfr < 2; kfr++)
#pragma unroll
                for (int dk = 0; dk < 2; dk++)
                    kfh[kfr][dk] = *(const half8*)(kp + (size_t)(kfr * 16 + lr) * 1024
                                                   + (h0 + hh) * 64 + dk * 32 + lh * 8);
            f32x4 sc[2][2] = {};
#pragma unroll
            for (int m = 0; m < 2; m++)
#pragma unroll
                for (int kfr = 0; kfr < 2; kfr++)
#pragma unroll
                    for (int dk = 0; dk < 2; dk++)
                        sc[m][kfr] = __builtin_amdgcn_mfma_f32_16x16x32_f16(
                            qf[hh][m][dk], kfh[kfr][dk], sc[m][kfr], 0, 0, 0);
#pragma unroll
            for (int m = 0; m < 2; m++)
#pragma unroll
                for (int kfr = 0; kfr < 2; kfr++)
#pragma unroll
                    for (int j = 0; j < 4; j++) {
                        float p = __builtin_amdgcn_exp2f(sc[m][kfr][j]) * rinv[hh][m][j];
                        psum[m][kfr][j] += p;
                        Pld[w][m * 16 + lh * 4 + j][kfr * 16 + lr] = (_Float16)p;
                    }
#pragma unroll
            for (int m = 0; m < 2; m++) {
                union { half8 v8; half4 v4[2]; } pu;
                pu.v4[0] = *(const half4*)&Pld[w][m * 16 + lr][lh * 8];
                pu.v4[1] = *(const half4*)&Pld[w][m * 16 + lr][lh * 8 + 4];
                half8 pa = pu.v8;
#pragma unroll
                for (int dv = 0; dv < 4; dv++)
                    oacc[hh][m][dv] = __builtin_amdgcn_mfma_f32_16x16x32_f16(
                        pa, vf[dv], oacc[hh][m][dv], 0, 0, 0);
            }
        }
#pragma unroll
        for (int m = 0; m < 2; m++)
#pragma unroll
            for (int kfr = 0; kfr < 2; kfr++)
#pragma unroll
                for (int j = 0; j < 4; j++)
                    pw[w][m * 16 + lh * 4 + j][kfr * 16 + lr] = psum[m][kfr][j];
        __syncthreads();
        for (int idx = tid; idx < 1024; idx += 512) {
            int r = idx >> 5, c = idx & 31;
            float s = 0.f;
#pragma unroll
            for (int ww = 0; ww < 8; ww++) s += pw[ww][r][c];
            __builtin_nontemporal_store(s * 0.0625f,
                &attn_out[(((size_t)(b * 2048 + q0 + r)) << 11) + krow + c]);
        }
        __syncthreads();
    }

    _Float16* op = Op + (size_t)ks * 8388608 + base;
#pragma unroll
    for (int hh = 0; hh < 2; hh++)
#pragma unroll
        for (int m = 0; m < 2; m++)
#pragma unroll
            for (int dv = 0; dv < 4; dv++)
#pragma unroll
                for (int j = 0; j < 4; j++) {
                    int row = q0 + m * 16 + lh * 4 + j;
                    int col = (h0 + hh) * 64 + dv * 16 + lr;
                    op[(size_t)row * 1024 + col] = (_Float16)oacc[hh][m][dv][j];
                }
}

extern "C" void kernel_launch(void* const* d_in, const int* in_sizes, int n_in,
                              void* d_out, int out_size, void* d_ws, size_t ws_size,
                              hipStream_t stream)
{
    const float* q  = (const float*)d_in[0];
    const float* k  = (const float*)d_in[1];
    const float* v  = (const float*)d_in[2];
    const float* Wq = (const float*)d_in[3];
    const float* bq = (const float*)d_in[4];
    const float* Wk = (const float*)d_in[5];
    const float* bk = (const float*)d_in[6];
    const float* Wv = (const float*)d_in[7];
    const float* bv = (const float*)d_in[8];
    const float* Wo = (const float*)d_in[9];
    const float* bo = (const float*)d_in[10];

    float* y = (float*)d_out;
    float* attn_mean = y + (size_t)4 * 2048 * 1024;

    uint8_t* ws = (uint8_t*)d_ws;
    _Float16* Qh  = (_Float16*)(ws);                         // 16 MB @ 0
    _Float16* Kh  = (_Float16*)(ws + 16777216);              // 16 MB
    _Float16* VT  = (_Float16*)(ws + 33554432);              // 1 MB
    _Float16* Wqc = (_Float16*)(ws + 34603008);              // 2 MB
    _Float16* Wkc = (_Float16*)(ws + 36700160);              // 2 MB
    _Float16* Woc = (_Float16*)(ws + 38797312);              // 2 MB
    _Float16* qc  = (_Float16*)(ws + 40894464);              // 16 MB (becomes Op0)
    _Float16* kc  = (_Float16*)(ws + 57671680);              // 16 MB (becomes Op1)
    _Float16* Op  = qc;
    _Float16* attnp = (_Float16*)(ws + 74448896);            // 64 MB (2 x 8-head f16 partials)

    const bool big = ws_size >= 141557760ull;

    const float QS = 0.125f * 1.44269504088896340736f;

    cvt_kernel<<<dim3(1024), dim3(256), 0, stream>>>(q, qc, 1048576);
    cvt_kernel<<<dim3(1024), dim3(256), 0, stream>>>(k, kc, 1048576);
    cvt_kernel<<<dim3(512),  dim3(256), 0, stream>>>(Wq, Wqc, 131072);
    cvt_kernel<<<dim3(512),  dim3(256), 0, stream>>>(Wk, Wkc, 131072);
    cvt_kernel<<<dim3(512),  dim3(256), 0, stream>>>(Wo, Woc, 131072);

    gemm16<true><<<dim3(64, 8), dim3(256), 0, stream>>>(qc, Wqc, bq, QS, Qh, 8192, 1024, 1024);
    gemm16<true><<<dim3(64, 8), dim3(256), 0, stream>>>(kc, Wkc, bk, 1.0f, Kh, 8192, 1024, 1024);
    gemm_vp<128, 64, 4, 1><<<dim3(1, 64), dim3(256), 0, stream>>>(v, Wv, bv, VT, 8192, 64, 1024);

    if (big) {
        attn2_kernel<<<dim3(1024), dim3(512), 0, stream>>>(Qh, Kh, VT, attnp, Op);
        combine_kernel<<<dim3(2048), dim3(256), 0, stream>>>(
            attnp, attnp + (size_t)16777216, attn_mean, 2097152);
    } else {
        attn_kernel<<<dim3(512), dim3(512), 0, stream>>>(Qh, Kh, VT, attn_mean, Op);
    }

    opsum_kernel<<<dim3(1024), dim3(256), 0, stream>>>(Op, Op + (size_t)8388608, Op, 1048576);

    gemm16<false><<<dim3(64, 8), dim3(256), 0, stream>>>(Op, Woc, bo, 1.0f, y, 8192, 1024, 1024);
}

// Round 8
// 626.522 us; speedup vs baseline: 1.1357x; 1.1357x over previous
//
#include <hip/hip_runtime.h>
#include <cstdint>
#include <cstddef>

typedef __attribute__((ext_vector_type(8))) _Float16 half8;
typedef __attribute__((ext_vector_type(4))) _Float16 half4;
typedef __attribute__((ext_vector_type(4))) float f32x4;

#define DEV static __device__ __forceinline__
#define AS1(p) (const __attribute__((address_space(1))) void*)(p)
#define AS3(p) (__attribute__((address_space(3))) void*)(p)

DEV half8 cvt8(const float* p) {
    f32x4 a = *(const f32x4*)p;
    f32x4 b = *(const f32x4*)(p + 4);
    half8 o;
    o[0] = (_Float16)a[0]; o[1] = (_Float16)a[1];
    o[2] = (_Float16)a[2]; o[3] = (_Float16)a[3];
    o[4] = (_Float16)b[0]; o[5] = (_Float16)b[1];
    o[6] = (_Float16)b[2]; o[7] = (_Float16)b[3];
    return o;
}

// ---- elementwise f32 -> f16 ----
__global__ __launch_bounds__(256)
void cvt_kernel(const float* __restrict__ in, _Float16* __restrict__ out, int n8)
{
    int i = blockIdx.x * 256 + threadIdx.x;
    int stride = gridDim.x * 256;
    for (; i < n8; i += stride)
        ((half8*)out)[i] = cvt8(in + (size_t)i * 8);
}

// ---- elementwise f16+f16 -> f16 (in-place safe) ----
__global__ __launch_bounds__(256)
void opsum_kernel(const _Float16* __restrict__ a, const _Float16* __restrict__ b,
                  _Float16* __restrict__ out, int n8)
{
    int i = blockIdx.x * 256 + threadIdx.x;
    int stride = gridDim.x * 256;
    for (; i < n8; i += stride) {
        half8 x = ((const half8*)a)[i];
        half8 y = ((const half8*)b)[i];
        half8 o;
#pragma unroll
        for (int j = 0; j < 8; j++) o[j] = (_Float16)((float)x[j] + (float)y[j]);
        ((half8*)out)[i] = o;
    }
}

// ---- combine: attn_mean = (hg0 + hg1) / 16, f16 partials -> f32 ----
__global__ __launch_bounds__(256)
void combine_kernel(const _Float16* __restrict__ a, const _Float16* __restrict__ b,
                    float* __restrict__ out, int n8)
{
    int i = blockIdx.x * 256 + threadIdx.x;
    int stride = gridDim.x * 256;
    for (; i < n8; i += stride) {
        half8 x = ((const half8*)a)[i];
        half8 y = ((const half8*)b)[i];
        f32x4 o0, o1;
#pragma unroll
        for (int j = 0; j < 4; j++) o0[j] = ((float)x[j] + (float)y[j]) * 0.0625f;
#pragma unroll
        for (int j = 0; j < 4; j++) o1[j] = ((float)x[j + 4] + (float)y[j + 4]) * 0.0625f;
        *(f32x4*)(out + (size_t)i * 8) = o0;
        *(f32x4*)(out + (size_t)i * 8 + 4) = o1;
    }
}

// ---- f16 GEMM with global_load_lds staging ----
template<bool OUT_F16>
__global__ __launch_bounds__(256, 2)
void gemm16(const _Float16* __restrict__ A, const _Float16* __restrict__ B,
            const float* __restrict__ bias, float scale, void* __restrict__ Cout,
            int M, int N, int K)
{
    __shared__ half8 As[2][512];
    __shared__ half8 Bs[2][512];
    const int tid = threadIdx.x, l = tid & 63, w = tid >> 6;
    const int lr = l & 15, lh = l >> 4;
    const int wm0 = (w >> 1) * 64, wn0 = (w & 1) * 64;
    const int bm0 = blockIdx.x * 128, bn0 = blockIdx.y * 128;
    const int nsteps = K >> 5;

    f32x4 acc[4][4] = {};

#define STAGE(buf, t) do {                                                        \
        int k0 = (t) << 5;                                                        \
        _Pragma("unroll")                                                         \
        for (int q2 = 0; q2 < 2; q2++) {                                          \
            int r = q2 * 64 + l;                                                  \
            __builtin_amdgcn_global_load_lds(                                     \
                AS1(A + (size_t)(bm0 + r) * K + k0 + w * 8),                      \
                AS3(&As[buf][w * 128 + q2 * 64]), 16, 0, 0);                      \
            __builtin_amdgcn_global_load_lds(                                     \
                AS1(B + (size_t)(bn0 + r) * K + k0 + w * 8),                      \
                AS3(&Bs[buf][w * 128 + q2 * 64]), 16, 0, 0);                      \
        }                                                                         \
    } while (0)

    STAGE(0, 0);
    __syncthreads();
    for (int t = 0; t < nsteps; t++) {
        int cur = t & 1;
        if (t + 1 < nsteps) STAGE(cur ^ 1, t + 1);
        half8 a[4], b[4];
#pragma unroll
        for (int m = 0; m < 4; m++) a[m] = As[cur][lh * 128 + wm0 + m * 16 + lr];
#pragma unroll
        for (int n = 0; n < 4; n++) b[n] = Bs[cur][lh * 128 + wn0 + n * 16 + lr];
#pragma unroll
        for (int m = 0; m < 4; m++)
#pragma unroll
            for (int n = 0; n < 4; n++)
                acc[m][n] = __builtin_amdgcn_mfma_f32_16x16x32_f16(a[m], b[n], acc[m][n], 0, 0, 0);
        __syncthreads();
    }
#undef STAGE

#pragma unroll
    for (int m = 0; m < 4; m++)
#pragma unroll
        for (int n = 0; n < 4; n++) {
            int row0 = bm0 + wm0 + m * 16 + lh * 4;
            int col = bn0 + wn0 + n * 16 + lr;
            float bv = bias[col];
#pragma unroll
            for (int j = 0; j < 4; j++) {
                float val = (acc[m][n][j] + bv) * scale;
                int row = row0 + j;
                if constexpr (OUT_F16)
                    ((_Float16*)Cout)[(size_t)row * N + col] = (_Float16)val;
                else
                    ((float*)Cout)[(size_t)row * N + col] = val;
            }
        }
}

// ---- legacy GEMM (f32 inputs) -- V projection, writes VT[b][dv][t] ----
template<int BM, int BN, int WR, int WC>
__global__ __launch_bounds__(256, 2)
void gemm_vp(const float* __restrict__ Aptr, const float* __restrict__ Bw,
             const float* __restrict__ bias, _Float16* __restrict__ Cout, int M, int N, int K)
{
    constexpr int BK = 32;
    constexpr int WM = BM / WR, WN = BN / WC;
    constexpr int MF = WM / 16, NF = WN / 16;
    constexpr int LDT = 40;
    __shared__ _Float16 Asl[BM][LDT];
    __shared__ _Float16 Bsl[BN][LDT];

    const int tid = threadIdx.x;
    const int l = tid & 63;
    const int w = tid >> 6;
    const int wr = w / WC, wc = w % WC;
    const int lr = l & 15, lh = l >> 4;
    const int bm0 = blockIdx.y * BM, bn0 = blockIdx.x * BN;

    f32x4 acc[MF][NF] = {};

    for (int k0 = 0; k0 < K; k0 += BK) {
        __syncthreads();
        for (int c = tid; c < BM * 4; c += 256) {
            int row = c >> 2, c8 = (c & 3) << 3;
            *(half8*)&Asl[row][c8] = cvt8(Aptr + (size_t)(bm0 + row) * K + k0 + c8);
        }
        for (int c = tid; c < BN * 4; c += 256) {
            int row = c >> 2, c8 = (c & 3) << 3;
            *(half8*)&Bsl[row][c8] = cvt8(Bw + (size_t)(bn0 + row) * K + k0 + c8);
        }
        __syncthreads();

        half8 a[MF], b[NF];
#pragma unroll
        for (int m = 0; m < MF; m++)
            a[m] = *(const half8*)&Asl[wr * WM + m * 16 + lr][lh * 8];
#pragma unroll
        for (int n = 0; n < NF; n++)
            b[n] = *(const half8*)&Bsl[wc * WN + n * 16 + lr][lh * 8];
#pragma unroll
        for (int m = 0; m < MF; m++)
#pragma unroll
            for (int n = 0; n < NF; n++)
                acc[m][n] = __builtin_amdgcn_mfma_f32_16x16x32_f16(a[m], b[n], acc[m][n], 0, 0, 0);
    }

#pragma unroll
    for (int m = 0; m < MF; m++)
#pragma unroll
        for (int n = 0; n < NF; n++) {
            int row0 = bm0 + wr * WM + m * 16 + lh * 4;
            int col = bn0 + wc * WN + n * 16 + lr;
            float bv = bias[col];
#pragma unroll
            for (int j = 0; j < 4; j++) {
                float val = acc[m][n][j] + bv;
                int row = row0 + j;
                int bi = row >> 11, t = row & 2047;
                Cout[(((size_t)(bi * 64 + col)) << 11) + t] = (_Float16)val;
            }
        }
}

// K-fragment loader shared by stats/emit: dst[kfr][dk], 4 x 16B global loads
#define LK(dst, kt) do {                                                          \
        const _Float16* kp_ = Kb + (size_t)((kt) * 32) * 1024;                    \
        _Pragma("unroll")                                                         \
        for (int kfr_ = 0; kfr_ < 2; kfr_++)                                      \
            _Pragma("unroll")                                                     \
            for (int dk_ = 0; dk_ < 2; dk_++)                                     \
                dst[kfr_][dk_] = *(const half8*)(kp_ + (size_t)(kfr_ * 16 + lr) * 1024 \
                                                 + ch + dk_ * 32 + lh * 8);       \
    } while (0)

// ---- stats: full-K softmax denominators. 1 head/wave, 32 q-rows, no LDS,
// no barriers, register ping-pong K prefetch. Grid 512 = 4b x 2hg x 64 qt
// (all-resident, 2 blocks/CU). Writes row-sums slp[b][h][q].
__global__ __launch_bounds__(512, 4)
void stats_kernel(const _Float16* __restrict__ Qh, const _Float16* __restrict__ Kh,
                  float* __restrict__ slp)
{
    const int blk = blockIdx.x;
    const int b = blk & 3;
    const int hg = (blk >> 2) & 1;
    const int q0 = (blk >> 3) << 5;
    const int tid = threadIdx.x;
    const int l = tid & 63, w = tid >> 6;
    const int lr = l & 15, lh = l >> 4;
    const int ch = (hg * 8 + w) * 64;

    const size_t base = (size_t)b * 2048 * 1024;
    const _Float16* Qb = Qh + base;
    const _Float16* Kb = Kh + base;

    half8 qf[2][2];
#pragma unroll
    for (int m = 0; m < 2; m++)
#pragma unroll
        for (int dk = 0; dk < 2; dk++)
            qf[m][dk] = *(const half8*)(Qb + (size_t)(q0 + m * 16 + lr) * 1024
                                        + ch + dk * 32 + lh * 8);

    float sl[2][4] = {};
    half8 ka[2][2], kb2[2][2];

#define SBODY(KF) do {                                                            \
        f32x4 sc[2][2] = {};                                                      \
        _Pragma("unroll")                                                         \
        for (int m = 0; m < 2; m++)                                               \
            _Pragma("unroll")                                                     \
            for (int kfr = 0; kfr < 2; kfr++)                                     \
                _Pragma("unroll")                                                 \
                for (int dk = 0; dk < 2; dk++)                                    \
                    sc[m][kfr] = __builtin_amdgcn_mfma_f32_16x16x32_f16(          \
                        qf[m][dk], KF[kfr][dk], sc[m][kfr], 0, 0, 0);             \
        _Pragma("unroll")                                                         \
        for (int m = 0; m < 2; m++)                                               \
            _Pragma("unroll")                                                     \
            for (int j = 0; j < 4; j++)                                           \
                sl[m][j] += __builtin_amdgcn_exp2f(sc[m][0][j])                   \
                          + __builtin_amdgcn_exp2f(sc[m][1][j]);                  \
    } while (0)

    LK(ka, 0);
    for (int kt = 0; kt < 64; kt += 2) {
        LK(kb2, kt + 1);
        SBODY(ka);
        LK(ka, kt + 2 < 64 ? kt + 2 : 63);
        SBODY(kb2);
    }
#undef SBODY

#pragma unroll
    for (int m = 0; m < 2; m++)
#pragma unroll
        for (int j = 0; j < 4; j++) {
            float s = sl[m][j];
#pragma unroll
            for (int d = 1; d < 16; d <<= 1)
                s += __shfl_xor(s, d, 64);
            if (lr == 0)
                slp[(size_t)(b * 16 + hg * 8 + w) * 2048 + q0 + m * 16 + lh * 4 + j] = s;
        }
}

// ---- emit: own k-half only, rinv from stats. 1 head/wave, 32 q-rows.
// Parity-double-buffered Pld (1 barrier/kt, no pw), K reg-prefetch,
// nontemporal attnp/Op stores. Grid 1024 = 4b x 2ks x 2hg x 64 qt.
__global__ __launch_bounds__(512, 4)
void emit_kernel(const _Float16* __restrict__ Qh, const _Float16* __restrict__ Kh,
                 const _Float16* __restrict__ VT, const float* __restrict__ slp,
                 _Float16* __restrict__ attnp, _Float16* __restrict__ Op)
{
    const int blk = blockIdx.x;
    const int b = blk & 3;
    const int ks = (blk >> 2) & 1;
    const int hg = (blk >> 3) & 1;
    const int q0 = (blk >> 4) << 5;
    const int tid = threadIdx.x;
    const int l = tid & 63, w = tid >> 6;
    const int lr = l & 15, lh = l >> 4;
    const int ch = (hg * 8 + w) * 64;

    __shared__ _Float16 Pld[2][8][32][44];   // parity-double-buffered P staging

    const size_t base = (size_t)b * 2048 * 1024;
    const _Float16* Qb = Qh + base;
    const _Float16* Kb = Kh + base;

    half8 qf[2][2];
#pragma unroll
    for (int m = 0; m < 2; m++)
#pragma unroll
        for (int dk = 0; dk < 2; dk++)
            qf[m][dk] = *(const half8*)(Qb + (size_t)(q0 + m * 16 + lr) * 1024
                                        + ch + dk * 32 + lh * 8);

    float rinv[2][4];
    {
        const float* sr = slp + (size_t)(b * 16 + hg * 8 + w) * 2048 + q0;
#pragma unroll
        for (int m = 0; m < 2; m++)
#pragma unroll
            for (int j = 0; j < 4; j++)
                rinv[m][j] = 1.0f / sr[m * 16 + lh * 4 + j];
    }

    f32x4 oacc[2][4] = {};
    const int kt0 = ks * 32;
    half8 ka[2][2], kb2[2][2];

#define EBODY(KF, KT, P) do {                                                     \
        const int krow = (KT) * 32;                                               \
        f32x4 sc[2][2] = {};                                                      \
        _Pragma("unroll")                                                         \
        for (int m = 0; m < 2; m++)                                               \
            _Pragma("unroll")                                                     \
            for (int kfr = 0; kfr < 2; kfr++)                                     \
                _Pragma("unroll")                                                 \
                for (int dk = 0; dk < 2; dk++)                                    \
                    sc[m][kfr] = __builtin_amdgcn_mfma_f32_16x16x32_f16(          \
                        qf[m][dk], KF[kfr][dk], sc[m][kfr], 0, 0, 0);             \
        _Pragma("unroll")                                                         \
        for (int m = 0; m < 2; m++)                                               \
            _Pragma("unroll")                                                     \
            for (int kfr = 0; kfr < 2; kfr++)                                     \
                _Pragma("unroll")                                                 \
                for (int j = 0; j < 4; j++) {                                     \
                    float pv = __builtin_amdgcn_exp2f(sc[m][kfr][j]) * rinv[m][j];\
                    Pld[P][w][m * 16 + lh * 4 + j][kfr * 16 + lr] = (_Float16)pv; \
                }                                                                 \
        half8 vf01[2], vf23[2], pa[2];                                            \
        _Pragma("unroll")                                                         \
        for (int dv = 0; dv < 2; dv++)                                            \
            vf01[dv] = *(const half8*)(VT + (((size_t)(b * 64 + dv * 16 + lr)) << 11) + krow + lh * 8); \
        _Pragma("unroll")                                                         \
        for (int m = 0; m < 2; m++) {                                             \
            union { half8 v8; half4 v4[2]; } pu;                                  \
            pu.v4[0] = *(const half4*)&Pld[P][w][m * 16 + lr][lh * 8];            \
            pu.v4[1] = *(const half4*)&Pld[P][w][m * 16 + lr][lh * 8 + 4];        \
            pa[m] = pu.v8;                                                        \
        }                                                                         \
        _Pragma("unroll")                                                         \
        for (int dv = 0; dv < 2; dv++)                                            \
            vf23[dv] = *(const half8*)(VT + (((size_t)(b * 64 + (dv + 2) * 16 + lr)) << 11) + krow + lh * 8); \
        _Pragma("unroll")                                                         \
        for (int m = 0; m < 2; m++)                                               \
            _Pragma("unroll")                                                     \
            for (int dv = 0; dv < 2; dv++)                                        \
                oacc[m][dv] = __builtin_amdgcn_mfma_f32_16x16x32_f16(             \
                    pa[m], vf01[dv], oacc[m][dv], 0, 0, 0);                       \
        _Pragma("unroll")                                                         \
        for (int m = 0; m < 2; m++)                                               \
            _Pragma("unroll")                                                     \
            for (int dv = 0; dv < 2; dv++)                                        \
                oacc[m][dv + 2] = __builtin_amdgcn_mfma_f32_16x16x32_f16(         \
                    pa[m], vf23[dv], oacc[m][dv + 2], 0, 0, 0);                   \
        __syncthreads();                                                          \
        {                                                                         \
            int r = tid >> 4, c2 = (tid & 15) * 2;                                \
            float s0 = 0.f, s1 = 0.f;                                             \
            _Pragma("unroll")                                                     \
            for (int ww = 0; ww < 8; ww++) {                                      \
                s0 += (float)Pld[P][ww][r][c2];                                   \
                s1 += (float)Pld[P][ww][r][c2 + 1];                               \
            }                                                                     \
            union { _Float16 h[2]; uint32_t u; } pk;                              \
            pk.h[0] = (_Float16)s0; pk.h[1] = (_Float16)s1;                       \
            __builtin_nontemporal_store(pk.u, (uint32_t*)(attnp                   \
                + (size_t)hg * 16777216 + (((size_t)(b * 2048 + q0 + r)) << 11)   \
                + krow + c2));                                                    \
        }                                                                         \
    } while (0)

    LK(ka, kt0);
    for (int i = 0; i < 32; i += 2) {
        LK(kb2, kt0 + i + 1);
        EBODY(ka, kt0 + i, 0);
        LK(ka, kt0 + (i + 2 < 32 ? i + 2 : 31));
        EBODY(kb2, kt0 + i + 1, 1);
    }
#undef EBODY

    // O partial for this k-half (normalized; halves sum via opsum)
    _Float16* op = Op + (size_t)ks * 8388608 + base;
#pragma unroll
    for (int m = 0; m < 2; m++)
#pragma unroll
        for (int dv = 0; dv < 4; dv++)
#pragma unroll
            for (int j = 0; j < 4; j++) {
                int row = q0 + m * 16 + lh * 4 + j;
                int col = ch + dv * 16 + lr;
                __builtin_nontemporal_store((_Float16)oacc[m][dv][j],
                                            &op[(size_t)row * 1024 + col]);
            }
}

extern "C" void kernel_launch(void* const* d_in, const int* in_sizes, int n_in,
                              void* d_out, int out_size, void* d_ws, size_t ws_size,
                              hipStream_t stream)
{
    const float* q  = (const float*)d_in[0];
    const float* k  = (const float*)d_in[1];
    const float* v  = (const float*)d_in[2];
    const float* Wq = (const float*)d_in[3];
    const float* bq = (const float*)d_in[4];
    const float* Wk = (const float*)d_in[5];
    const float* bk = (const float*)d_in[6];
    const float* Wv = (const float*)d_in[7];
    const float* bv = (const float*)d_in[8];
    const float* Wo = (const float*)d_in[9];
    const float* bo = (const float*)d_in[10];

    float* y = (float*)d_out;
    float* attn_mean = y + (size_t)4 * 2048 * 1024;

    uint8_t* ws = (uint8_t*)d_ws;
    _Float16* Qh  = (_Float16*)(ws);                         // 16 MB @ 0
    _Float16* Kh  = (_Float16*)(ws + 16777216);              // 16 MB
    _Float16* VT  = (_Float16*)(ws + 33554432);              // 1 MB
    _Float16* Wqc = (_Float16*)(ws + 34603008);              // 2 MB (dead after Q-proj -> slp)
    _Float16* Wkc = (_Float16*)(ws + 36700160);              // 2 MB
    _Float16* Woc = (_Float16*)(ws + 38797312);              // 2 MB
    _Float16* qc  = (_Float16*)(ws + 40894464);              // 16 MB (becomes Op0)
    _Float16* kc  = (_Float16*)(ws + 57671680);              // 16 MB (becomes Op1)
    _Float16* Op  = qc;
    _Float16* attnp = (_Float16*)(ws + 74448896);            // 64 MB (2 hg partials)
    float*    slp = (float*)(ws + 34603008);                 // 512 KB over dead Wqc

    const float QS = 0.125f * 1.44269504088896340736f;

    cvt_kernel<<<dim3(1024), dim3(256), 0, stream>>>(q, qc, 1048576);
    cvt_kernel<<<dim3(1024), dim3(256), 0, stream>>>(k, kc, 1048576);
    cvt_kernel<<<dim3(512),  dim3(256), 0, stream>>>(Wq, Wqc, 131072);
    cvt_kernel<<<dim3(512),  dim3(256), 0, stream>>>(Wk, Wkc, 131072);
    cvt_kernel<<<dim3(512),  dim3(256), 0, stream>>>(Wo, Woc, 131072);

    gemm16<true><<<dim3(64, 8), dim3(256), 0, stream>>>(qc, Wqc, bq, QS, Qh, 8192, 1024, 1024);
    gemm16<true><<<dim3(64, 8), dim3(256), 0, stream>>>(kc, Wkc, bk, 1.0f, Kh, 8192, 1024, 1024);
    gemm_vp<128, 64, 4, 1><<<dim3(1, 64), dim3(256), 0, stream>>>(v, Wv, bv, VT, 8192, 64, 1024);

    stats_kernel<<<dim3(512), dim3(512), 0, stream>>>(Qh, Kh, slp);
    emit_kernel<<<dim3(1024), dim3(512), 0, stream>>>(Qh, Kh, VT, slp, attnp, Op);

    combine_kernel<<<dim3(2048), dim3(256), 0, stream>>>(
        attnp, attnp + (size_t)16777216, attn_mean, 2097152);
    opsum_kernel<<<dim3(1024), dim3(256), 0, stream>>>(Op, Op + (size_t)8388608, Op, 1048576);

    gemm16<false><<<dim3(64, 8), dim3(256), 0, stream>>>(Op, Woc, bo, 1.0f, y, 8192, 1024, 1024);
}

// Round 9
// 604.350 us; speedup vs baseline: 1.1774x; 1.0367x over previous
//
#include <hip/hip_runtime.h>
#include <cstdint>
#include <cstddef>

typedef __attribute__((ext_vector_type(8))) _Float16 half8;
typedef __attribute__((ext_vector_type(4))) _Float16 half4;
typedef __attribute__((ext_vector_type(4))) float f32x4;

#define DEV static __device__ __forceinline__
#define AS1(p) (const __attribute__((address_space(1))) void*)(p)
#define AS3(p) (__attribute__((address_space(3))) void*)(p)

DEV half8 cvt8(const float* p) {
    f32x4 a = *(const f32x4*)p;
    f32x4 b = *(const f32x4*)(p + 4);
    half8 o;
    o[0] = (_Float16)a[0]; o[1] = (_Float16)a[1];
    o[2] = (_Float16)a[2]; o[3] = (_Float16)a[3];
    o[4] = (_Float16)b[0]; o[5] = (_Float16)b[1];
    o[6] = (_Float16)b[2]; o[7] = (_Float16)b[3];
    return o;
}

// ---- f32 -> f16 for two buffers in one launch (q and k) ----
__global__ __launch_bounds__(256)
void cvt2_kernel(const float* __restrict__ a, _Float16* __restrict__ oa,
                 const float* __restrict__ b, _Float16* __restrict__ ob, int n8)
{
    int i = blockIdx.x * 256 + threadIdx.x;
    int stride = gridDim.x * 256;
    for (; i < 2 * n8; i += stride) {
        if (i < n8) ((half8*)oa)[i] = cvt8(a + (size_t)i * 8);
        else        ((half8*)ob)[i - n8] = cvt8(b + (size_t)(i - n8) * 8);
    }
}

// ---- f32 -> f16 for three weight matrices in one launch ----
__global__ __launch_bounds__(256)
void cvt3_kernel(const float* __restrict__ a, _Float16* __restrict__ oa,
                 const float* __restrict__ b, _Float16* __restrict__ ob,
                 const float* __restrict__ c, _Float16* __restrict__ oc, int n8)
{
    int i = blockIdx.x * 256 + threadIdx.x;
    int stride = gridDim.x * 256;
    for (; i < 3 * n8; i += stride) {
        if (i < n8)           ((half8*)oa)[i] = cvt8(a + (size_t)i * 8);
        else if (i < 2 * n8)  ((half8*)ob)[i - n8] = cvt8(b + (size_t)(i - n8) * 8);
        else                  ((half8*)oc)[i - 2 * n8] = cvt8(c + (size_t)(i - 2 * n8) * 8);
    }
}

// ---- combine: attn_mean = (hg0 + hg1) / 16, f16 partials -> f32 ----
__global__ __launch_bounds__(256)
void combine_kernel(const _Float16* __restrict__ a, const _Float16* __restrict__ b,
                    float* __restrict__ out, int n8)
{
    int i = blockIdx.x * 256 + threadIdx.x;
    int stride = gridDim.x * 256;
    for (; i < n8; i += stride) {
        half8 x = ((const half8*)a)[i];
        half8 y = ((const half8*)b)[i];
        f32x4 o0, o1;
#pragma unroll
        for (int j = 0; j < 4; j++) o0[j] = ((float)x[j] + (float)y[j]) * 0.0625f;
#pragma unroll
        for (int j = 0; j < 4; j++) o1[j] = ((float)x[j + 4] + (float)y[j + 4]) * 0.0625f;
        *(f32x4*)(out + (size_t)i * 8) = o0;
        *(f32x4*)(out + (size_t)i * 8 + 4) = o1;
    }
}

// ---- f16 GEMM with global_load_lds staging ----
template<bool OUT_F16>
__global__ __launch_bounds__(256, 2)
void gemm16(const _Float16* __restrict__ A, const _Float16* __restrict__ B,
            const float* __restrict__ bias, float scale, void* __restrict__ Cout,
            int M, int N, int K)
{
    __shared__ half8 As[2][512];
    __shared__ half8 Bs[2][512];
    const int tid = threadIdx.x, l = tid & 63, w = tid >> 6;
    const int lr = l & 15, lh = l >> 4;
    const int wm0 = (w >> 1) * 64, wn0 = (w & 1) * 64;
    const int bm0 = blockIdx.x * 128, bn0 = blockIdx.y * 128;
    const int nsteps = K >> 5;

    f32x4 acc[4][4] = {};

#define STAGE(buf, t) do {                                                        \
        int k0 = (t) << 5;                                                        \
        _Pragma("unroll")                                                         \
        for (int q2 = 0; q2 < 2; q2++) {                                          \
            int r = q2 * 64 + l;                                                  \
            __builtin_amdgcn_global_load_lds(                                     \
                AS1(A + (size_t)(bm0 + r) * K + k0 + w * 8),                      \
                AS3(&As[buf][w * 128 + q2 * 64]), 16, 0, 0);                      \
            __builtin_amdgcn_global_load_lds(                                     \
                AS1(B + (size_t)(bn0 + r) * K + k0 + w * 8),                      \
                AS3(&Bs[buf][w * 128 + q2 * 64]), 16, 0, 0);                      \
        }                                                                         \
    } while (0)

    STAGE(0, 0);
    __syncthreads();
    for (int t = 0; t < nsteps; t++) {
        int cur = t & 1;
        if (t + 1 < nsteps) STAGE(cur ^ 1, t + 1);
        half8 a[4], b[4];
#pragma unroll
        for (int m = 0; m < 4; m++) a[m] = As[cur][lh * 128 + wm0 + m * 16 + lr];
#pragma unroll
        for (int n = 0; n < 4; n++) b[n] = Bs[cur][lh * 128 + wn0 + n * 16 + lr];
#pragma unroll
        for (int m = 0; m < 4; m++)
#pragma unroll
            for (int n = 0; n < 4; n++)
                acc[m][n] = __builtin_amdgcn_mfma_f32_16x16x32_f16(a[m], b[n], acc[m][n], 0, 0, 0);
        __syncthreads();
    }
#undef STAGE

#pragma unroll
    for (int m = 0; m < 4; m++)
#pragma unroll
        for (int n = 0; n < 4; n++) {
            int row0 = bm0 + wm0 + m * 16 + lh * 4;
            int col = bn0 + wn0 + n * 16 + lr;
            float bv = bias[col];
#pragma unroll
            for (int j = 0; j < 4; j++) {
                float val = (acc[m][n][j] + bv) * scale;
                int row = row0 + j;
                if constexpr (OUT_F16)
                    ((_Float16*)Cout)[(size_t)row * N + col] = (_Float16)val;
                else
                    ((float*)Cout)[(size_t)row * N + col] = val;
            }
        }
}

// ---- legacy GEMM (f32 inputs) -- V projection, writes VT[b][dv][t] ----
template<int BM, int BN, int WR, int WC>
__global__ __launch_bounds__(256, 2)
void gemm_vp(const float* __restrict__ Aptr, const float* __restrict__ Bw,
             const float* __restrict__ bias, _Float16* __restrict__ Cout, int M, int N, int K)
{
    constexpr int BK = 32;
    constexpr int WM = BM / WR, WN = BN / WC;
    constexpr int MF = WM / 16, NF = WN / 16;
    constexpr int LDT = 40;
    __shared__ _Float16 Asl[BM][LDT];
    __shared__ _Float16 Bsl[BN][LDT];

    const int tid = threadIdx.x;
    const int l = tid & 63;
    const int w = tid >> 6;
    const int wr = w / WC, wc = w % WC;
    const int lr = l & 15, lh = l >> 4;
    const int bm0 = blockIdx.y * BM, bn0 = blockIdx.x * BN;

    f32x4 acc[MF][NF] = {};

    for (int k0 = 0; k0 < K; k0 += BK) {
        __syncthreads();
        for (int c = tid; c < BM * 4; c += 256) {
            int row = c >> 2, c8 = (c & 3) << 3;
            *(half8*)&Asl[row][c8] = cvt8(Aptr + (size_t)(bm0 + row) * K + k0 + c8);
        }
        for (int c = tid; c < BN * 4; c += 256) {
            int row = c >> 2, c8 = (c & 3) << 3;
            *(half8*)&Bsl[row][c8] = cvt8(Bw + (size_t)(bn0 + row) * K + k0 + c8);
        }
        __syncthreads();

        half8 a[MF], b[NF];
#pragma unroll
        for (int m = 0; m < MF; m++)
            a[m] = *(const half8*)&Asl[wr * WM + m * 16 + lr][lh * 8];
#pragma unroll
        for (int n = 0; n < NF; n++)
            b[n] = *(const half8*)&Bsl[wc * WN + n * 16 + lr][lh * 8];
#pragma unroll
        for (int m = 0; m < MF; m++)
#pragma unroll
            for (int n = 0; n < NF; n++)
                acc[m][n] = __builtin_amdgcn_mfma_f32_16x16x32_f16(a[m], b[n], acc[m][n], 0, 0, 0);
    }

#pragma unroll
    for (int m = 0; m < MF; m++)
#pragma unroll
        for (int n = 0; n < NF; n++) {
            int row0 = bm0 + wr * WM + m * 16 + lh * 4;
            int col = bn0 + wc * WN + n * 16 + lr;
            float bv = bias[col];
#pragma unroll
            for (int j = 0; j < 4; j++) {
                float val = acc[m][n][j] + bv;
                int row = row0 + j;
                int bi = row >> 11, t = row & 2047;
                Cout[(((size_t)(bi * 64 + col)) << 11) + t] = (_Float16)val;
            }
        }
}

// K-fragment loader shared by stats/emit: dst[kfr][dk], 4 x 16B global loads
#define LK(dst, kt) do {                                                          \
        const _Float16* kp_ = Kb + (size_t)((kt) * 32) * 1024;                    \
        _Pragma("unroll")                                                         \
        for (int kfr_ = 0; kfr_ < 2; kfr_++)                                      \
            _Pragma("unroll")                                                     \
            for (int dk_ = 0; dk_ < 2; dk_++)                                     \
                dst[kfr_][dk_] = *(const half8*)(kp_ + (size_t)(kfr_ * 16 + lr) * 1024 \
                                                 + ch + dk_ * 32 + lh * 8);       \
    } while (0)

// ---- stats: full-K softmax denominators. 1 head/wave, 32 q-rows, no LDS,
// no barriers, register ping-pong K prefetch. Grid 512 = 4b x 2hg x 64 qt.
__global__ __launch_bounds__(512, 4)
void stats_kernel(const _Float16* __restrict__ Qh, const _Float16* __restrict__ Kh,
                  float* __restrict__ slp)
{
    const int blk = blockIdx.x;
    const int b = blk & 3;
    const int hg = (blk >> 2) & 1;
    const int q0 = (blk >> 3) << 5;
    const int tid = threadIdx.x;
    const int l = tid & 63, w = tid >> 6;
    const int lr = l & 15, lh = l >> 4;
    const int ch = (hg * 8 + w) * 64;

    const size_t base = (size_t)b * 2048 * 1024;
    const _Float16* Qb = Qh + base;
    const _Float16* Kb = Kh + base;

    half8 qf[2][2];
#pragma unroll
    for (int m = 0; m < 2; m++)
#pragma unroll
        for (int dk = 0; dk < 2; dk++)
            qf[m][dk] = *(const half8*)(Qb + (size_t)(q0 + m * 16 + lr) * 1024
                                        + ch + dk * 32 + lh * 8);

    float sl[2][4] = {};
    half8 ka[2][2], kb2[2][2];

#define SBODY(KF) do {                                                            \
        f32x4 sc[2][2] = {};                                                      \
        _Pragma("unroll")                                                         \
        for (int m = 0; m < 2; m++)                                               \
            _Pragma("unroll")                                                     \
            for (int kfr = 0; kfr < 2; kfr++)                                     \
                _Pragma("unroll")                                                 \
                for (int dk = 0; dk < 2; dk++)                                    \
                    sc[m][kfr] = __builtin_amdgcn_mfma_f32_16x16x32_f16(          \
                        qf[m][dk], KF[kfr][dk], sc[m][kfr], 0, 0, 0);             \
        _Pragma("unroll")                                                         \
        for (int m = 0; m < 2; m++)                                               \
            _Pragma("unroll")                                                     \
            for (int j = 0; j < 4; j++)                                           \
                sl[m][j] += __builtin_amdgcn_exp2f(sc[m][0][j])                   \
                          + __builtin_amdgcn_exp2f(sc[m][1][j]);                  \
    } while (0)

    LK(ka, 0);
    for (int kt = 0; kt < 64; kt += 2) {
        LK(kb2, kt + 1);
        SBODY(ka);
        LK(ka, kt + 2 < 64 ? kt + 2 : 63);
        SBODY(kb2);
    }
#undef SBODY

#pragma unroll
    for (int m = 0; m < 2; m++)
#pragma unroll
        for (int j = 0; j < 4; j++) {
            float s = sl[m][j];
#pragma unroll
            for (int d = 1; d < 16; d <<= 1)
                s += __shfl_xor(s, d, 64);
            if (lr == 0)
                slp[(size_t)(b * 16 + hg * 8 + w) * 2048 + q0 + m * 16 + lh * 4 + j] = s;
        }
}

// ---- emit: FULL-K sweep per block (no ks split). 1 head/wave, 32 q-rows.
// Grid 512 = 4b x 2hg x 64 qt = exactly 2 blocks/CU, single round.
// Parity-double-buffered Pld (1 barrier/kt), K reg-prefetch.
// attnp stores NT (read once later; keeps K L2-hot); Op stores cached (re-read).
__global__ __launch_bounds__(512, 4)
void emit_kernel(const _Float16* __restrict__ Qh, const _Float16* __restrict__ Kh,
                 const _Float16* __restrict__ VT, const float* __restrict__ slp,
                 _Float16* __restrict__ attnp, _Float16* __restrict__ Op)
{
    const int blk = blockIdx.x;
    const int b = blk & 3;
    const int hg = (blk >> 2) & 1;
    const int q0 = (blk >> 3) << 5;
    const int tid = threadIdx.x;
    const int l = tid & 63, w = tid >> 6;
    const int lr = l & 15, lh = l >> 4;
    const int ch = (hg * 8 + w) * 64;

    __shared__ _Float16 Pld[2][8][32][44];   // parity-double-buffered P staging

    const size_t base = (size_t)b * 2048 * 1024;
    const _Float16* Qb = Qh + base;
    const _Float16* Kb = Kh + base;

    half8 qf[2][2];
#pragma unroll
    for (int m = 0; m < 2; m++)
#pragma unroll
        for (int dk = 0; dk < 2; dk++)
            qf[m][dk] = *(const half8*)(Qb + (size_t)(q0 + m * 16 + lr) * 1024
                                        + ch + dk * 32 + lh * 8);

    float rinv[2][4];
    {
        const float* sr = slp + (size_t)(b * 16 + hg * 8 + w) * 2048 + q0;
#pragma unroll
        for (int m = 0; m < 2; m++)
#pragma unroll
            for (int j = 0; j < 4; j++)
                rinv[m][j] = 1.0f / sr[m * 16 + lh * 4 + j];
    }

    f32x4 oacc[2][4] = {};
    half8 ka[2][2], kb2[2][2];

#define EBODY(KF, KT, P) do {                                                     \
        const int krow = (KT) * 32;                                               \
        f32x4 sc[2][2] = {};                                                      \
        _Pragma("unroll")                                                         \
        for (int m = 0; m < 2; m++)                                               \
            _Pragma("unroll")                                                     \
            for (int kfr = 0; kfr < 2; kfr++)                                     \
                _Pragma("unroll")                                                 \
                for (int dk = 0; dk < 2; dk++)                                    \
                    sc[m][kfr] = __builtin_amdgcn_mfma_f32_16x16x32_f16(          \
                        qf[m][dk], KF[kfr][dk], sc[m][kfr], 0, 0, 0);             \
        _Pragma("unroll")                                                         \
        for (int m = 0; m < 2; m++)                                               \
            _Pragma("unroll")                                                     \
            for (int kfr = 0; kfr < 2; kfr++)                                     \
                _Pragma("unroll")                                                 \
                for (int j = 0; j < 4; j++) {                                     \
                    float pv = __builtin_amdgcn_exp2f(sc[m][kfr][j]) * rinv[m][j];\
                    Pld[P][w][m * 16 + lh * 4 + j][kfr * 16 + lr] = (_Float16)pv; \
                }                                                                 \
        half8 vf01[2], vf23[2], pa[2];                                            \
        _Pragma("unroll")                                                         \
        for (int dv = 0; dv < 2; dv++)                                            \
            vf01[dv] = *(const half8*)(VT + (((size_t)(b * 64 + dv * 16 + lr)) << 11) + krow + lh * 8); \
        _Pragma("unroll")                                                         \
        for (int m = 0; m < 2; m++) {                                             \
            union { half8 v8; half4 v4[2]; } pu;                                  \
            pu.v4[0] = *(const half4*)&Pld[P][w][m * 16 + lr][lh * 8];            \
            pu.v4[1] = *(const half4*)&Pld[P][w][m * 16 + lr][lh * 8 + 4];        \
            pa[m] = pu.v8;                                                        \
        }                                                                         \
        _Pragma("unroll")                                                         \
        for (int dv = 0; dv < 2; dv++)                                            \
            vf23[dv] = *(const half8*)(VT + (((size_t)(b * 64 + (dv + 2) * 16 + lr)) << 11) + krow + lh * 8); \
        _Pragma("unroll")                                                         \
        for (int m = 0; m < 2; m++)                                               \
            _Pragma("unroll")                                                     \
            for (int dv = 0; dv < 2; dv++)                                        \
                oacc[m][dv] = __builtin_amdgcn_mfma_f32_16x16x32_f16(             \
                    pa[m], vf01[dv], oacc[m][dv], 0, 0, 0);                       \
        _Pragma("unroll")                                                         \
        for (int m = 0; m < 2; m++)                                               \
            _Pragma("unroll")                                                     \
            for (int dv = 0; dv < 2; dv++)                                        \
                oacc[m][dv + 2] = __builtin_amdgcn_mfma_f32_16x16x32_f16(         \
                    pa[m], vf23[dv], oacc[m][dv + 2], 0, 0, 0);                   \
        __syncthreads();                                                          \
        {                                                                         \
            int r = tid >> 4, c2 = (tid & 15) * 2;                                \
            float s0 = 0.f, s1 = 0.f;                                             \
            _Pragma("unroll")                                                     \
            for (int ww = 0; ww < 8; ww++) {                                      \
                s0 += (float)Pld[P][ww][r][c2];                                   \
                s1 += (float)Pld[P][ww][r][c2 + 1];                               \
            }                                                                     \
            union { _Float16 h[2]; uint32_t u; } pk;                              \
            pk.h[0] = (_Float16)s0; pk.h[1] = (_Float16)s1;                       \
            __builtin_nontemporal_store(pk.u, (uint32_t*)(attnp                   \
                + (size_t)hg * 16777216 + (((size_t)(b * 2048 + q0 + r)) << 11)   \
                + krow + c2));                                                    \
        }                                                                         \
    } while (0)

    LK(ka, 0);
    for (int i = 0; i < 64; i += 2) {
        LK(kb2, i + 1);
        EBODY(ka, i, 0);
        LK(ka, i + 2 < 64 ? i + 2 : 63);
        EBODY(kb2, i + 1, 1);
    }
#undef EBODY

    // O (full-K, normalized) -- cached stores, re-read by the y-GEMM
    _Float16* op = Op + base;
#pragma unroll
    for (int m = 0; m < 2; m++)
#pragma unroll
        for (int dv = 0; dv < 4; dv++)
#pragma unroll
            for (int j = 0; j < 4; j++) {
                int row = q0 + m * 16 + lh * 4 + j;
                int col = ch + dv * 16 + lr;
                op[(size_t)row * 1024 + col] = (_Float16)oacc[m][dv][j];
            }
}

extern "C" void kernel_launch(void* const* d_in, const int* in_sizes, int n_in,
                              void* d_out, int out_size, void* d_ws, size_t ws_size,
                              hipStream_t stream)
{
    const float* q  = (const float*)d_in[0];
    const float* k  = (const float*)d_in[1];
    const float* v  = (const float*)d_in[2];
    const float* Wq = (const float*)d_in[3];
    const float* bq = (const float*)d_in[4];
    const float* Wk = (const float*)d_in[5];
    const float* bk = (const float*)d_in[6];
    const float* Wv = (const float*)d_in[7];
    const float* bv = (const float*)d_in[8];
    const float* Wo = (const float*)d_in[9];
    const float* bo = (const float*)d_in[10];

    float* y = (float*)d_out;
    float* attn_mean = y + (size_t)4 * 2048 * 1024;

    uint8_t* ws = (uint8_t*)d_ws;
    _Float16* Qh  = (_Float16*)(ws);                         // 16 MB @ 0
    _Float16* Kh  = (_Float16*)(ws + 16777216);              // 16 MB
    _Float16* VT  = (_Float16*)(ws + 33554432);              // 1 MB
    _Float16* Wqc = (_Float16*)(ws + 34603008);              // 2 MB (dead after Q-proj -> slp)
    _Float16* Wkc = (_Float16*)(ws + 36700160);              // 2 MB
    _Float16* Woc = (_Float16*)(ws + 38797312);              // 2 MB
    _Float16* qc  = (_Float16*)(ws + 40894464);              // 16 MB (becomes Op)
    _Float16* kc  = (_Float16*)(ws + 57671680);              // 16 MB
    _Float16* Op  = qc;
    _Float16* attnp = (_Float16*)(ws + 74448896);            // 64 MB (2 hg partials)
    float*    slp = (float*)(ws + 34603008);                 // 512 KB over dead Wqc

    const float QS = 0.125f * 1.44269504088896340736f;

    cvt2_kernel<<<dim3(2048), dim3(256), 0, stream>>>(q, qc, k, kc, 1048576);
    cvt3_kernel<<<dim3(512),  dim3(256), 0, stream>>>(Wq, Wqc, Wk, Wkc, Wo, Woc, 131072);

    gemm16<true><<<dim3(64, 8), dim3(256), 0, stream>>>(qc, Wqc, bq, QS, Qh, 8192, 1024, 1024);
    gemm16<true><<<dim3(64, 8), dim3(256), 0, stream>>>(kc, Wkc, bk, 1.0f, Kh, 8192, 1024, 1024);
    gemm_vp<128, 64, 4, 1><<<dim3(1, 64), dim3(256), 0, stream>>>(v, Wv, bv, VT, 8192, 64, 1024);

    stats_kernel<<<dim3(512), dim3(512), 0, stream>>>(Qh, Kh, slp);
    emit_kernel<<<dim3(512), dim3(512), 0, stream>>>(Qh, Kh, VT, slp, attnp, Op);

    combine_kernel<<<dim3(2048), dim3(256), 0, stream>>>(
        attnp, attnp + (size_t)16777216, attn_mean, 2097152);

    gemm16<false><<<dim3(64, 8), dim3(256), 0, stream>>>(Op, Woc, bo, 1.0f, y, 8192, 1024, 1024);
}

// Round 10
// 570.173 us; speedup vs baseline: 1.2480x; 1.0599x over previous
//
#include <hip/hip_runtime.h>
#include <cstdint>
#include <cstddef>

typedef __attribute__((ext_vector_type(8))) _Float16 half8;
typedef __attribute__((ext_vector_type(4))) _Float16 half4;
typedef __attribute__((ext_vector_type(4))) float f32x4;

#define DEV static __device__ __forceinline__
#define AS1(p) (const __attribute__((address_space(1))) void*)(p)
#define AS3(p) (__attribute__((address_space(3))) void*)(p)

DEV half8 cvt8(const float* p) {
    f32x4 a = *(const f32x4*)p;
    f32x4 b = *(const f32x4*)(p + 4);
    half8 o;
    o[0] = (_Float16)a[0]; o[1] = (_Float16)a[1];
    o[2] = (_Float16)a[2]; o[3] = (_Float16)a[3];
    o[4] = (_Float16)b[0]; o[5] = (_Float16)b[1];
    o[6] = (_Float16)b[2]; o[7] = (_Float16)b[3];
    return o;
}

// ---- f32 -> f16 for two buffers in one launch (q and k) ----
__global__ __launch_bounds__(256)
void cvt2_kernel(const float* __restrict__ a, _Float16* __restrict__ oa,
                 const float* __restrict__ b, _Float16* __restrict__ ob, int n8)
{
    int i = blockIdx.x * 256 + threadIdx.x;
    int stride = gridDim.x * 256;
    for (; i < 2 * n8; i += stride) {
        if (i < n8) ((half8*)oa)[i] = cvt8(a + (size_t)i * 8);
        else        ((half8*)ob)[i - n8] = cvt8(b + (size_t)(i - n8) * 8);
    }
}

// ---- f32 -> f16 for three weight matrices in one launch ----
__global__ __launch_bounds__(256)
void cvt3_kernel(const float* __restrict__ a, _Float16* __restrict__ oa,
                 const float* __restrict__ b, _Float16* __restrict__ ob,
                 const float* __restrict__ c, _Float16* __restrict__ oc, int n8)
{
    int i = blockIdx.x * 256 + threadIdx.x;
    int stride = gridDim.x * 256;
    for (; i < 3 * n8; i += stride) {
        if (i < n8)           ((half8*)oa)[i] = cvt8(a + (size_t)i * 8);
        else if (i < 2 * n8)  ((half8*)ob)[i - n8] = cvt8(b + (size_t)(i - n8) * 8);
        else                  ((half8*)oc)[i - 2 * n8] = cvt8(c + (size_t)(i - 2 * n8) * 8);
    }
}

// ---- combine: attn_mean = (hg0 + hg1) / 16, f16 partials -> f32 ----
__global__ __launch_bounds__(256)
void combine_kernel(const _Float16* __restrict__ a, const _Float16* __restrict__ b,
                    float* __restrict__ out, int n8)
{
    int i = blockIdx.x * 256 + threadIdx.x;
    int stride = gridDim.x * 256;
    for (; i < n8; i += stride) {
        half8 x = ((const half8*)a)[i];
        half8 y = ((const half8*)b)[i];
        f32x4 o0, o1;
#pragma unroll
        for (int j = 0; j < 4; j++) o0[j] = ((float)x[j] + (float)y[j]) * 0.0625f;
#pragma unroll
        for (int j = 0; j < 4; j++) o1[j] = ((float)x[j + 4] + (float)y[j + 4]) * 0.0625f;
        *(f32x4*)(out + (size_t)i * 8) = o0;
        *(f32x4*)(out + (size_t)i * 8 + 4) = o1;
    }
}

// ---- f16 GEMM with global_load_lds staging ----
template<bool OUT_F16>
__global__ __launch_bounds__(256, 2)
void gemm16(const _Float16* __restrict__ A, const _Float16* __restrict__ B,
            const float* __restrict__ bias, float scale, void* __restrict__ Cout,
            int M, int N, int K)
{
    __shared__ half8 As[2][512];
    __shared__ half8 Bs[2][512];
    const int tid = threadIdx.x, l = tid & 63, w = tid >> 6;
    const int lr = l & 15, lh = l >> 4;
    const int wm0 = (w >> 1) * 64, wn0 = (w & 1) * 64;
    const int bm0 = blockIdx.x * 128, bn0 = blockIdx.y * 128;
    const int nsteps = K >> 5;

    f32x4 acc[4][4] = {};

#define STAGE(buf, t) do {                                                        \
        int k0 = (t) << 5;                                                        \
        _Pragma("unroll")                                                         \
        for (int q2 = 0; q2 < 2; q2++) {                                          \
            int r = q2 * 64 + l;                                                  \
            __builtin_amdgcn_global_load_lds(                                     \
                AS1(A + (size_t)(bm0 + r) * K + k0 + w * 8),                      \
                AS3(&As[buf][w * 128 + q2 * 64]), 16, 0, 0);                      \
            __builtin_amdgcn_global_load_lds(                                     \
                AS1(B + (size_t)(bn0 + r) * K + k0 + w * 8),                      \
                AS3(&Bs[buf][w * 128 + q2 * 64]), 16, 0, 0);                      \
        }                                                                         \
    } while (0)

    STAGE(0, 0);
    __syncthreads();
    for (int t = 0; t < nsteps; t++) {
        int cur = t & 1;
        if (t + 1 < nsteps) STAGE(cur ^ 1, t + 1);
        half8 a[4], b[4];
#pragma unroll
        for (int m = 0; m < 4; m++) a[m] = As[cur][lh * 128 + wm0 + m * 16 + lr];
#pragma unroll
        for (int n = 0; n < 4; n++) b[n] = Bs[cur][lh * 128 + wn0 + n * 16 + lr];
#pragma unroll
        for (int m = 0; m < 4; m++)
#pragma unroll
            for (int n = 0; n < 4; n++)
                acc[m][n] = __builtin_amdgcn_mfma_f32_16x16x32_f16(a[m], b[n], acc[m][n], 0, 0, 0);
        __syncthreads();
    }
#undef STAGE

#pragma unroll
    for (int m = 0; m < 4; m++)
#pragma unroll
        for (int n = 0; n < 4; n++) {
            int row0 = bm0 + wm0 + m * 16 + lh * 4;
            int col = bn0 + wn0 + n * 16 + lr;
            float bv = bias[col];
#pragma unroll
            for (int j = 0; j < 4; j++) {
                float val = (acc[m][n][j] + bv) * scale;
                int row = row0 + j;
                if constexpr (OUT_F16)
                    ((_Float16*)Cout)[(size_t)row * N + col] = (_Float16)val;
                else
                    ((float*)Cout)[(size_t)row * N + col] = val;
            }
        }
}

// ---- legacy GEMM (f32 inputs) -- V projection, writes VT[b][dv][t] ----
template<int BM, int BN, int WR, int WC>
__global__ __launch_bounds__(256, 2)
void gemm_vp(const float* __restrict__ Aptr, const float* __restrict__ Bw,
             const float* __restrict__ bias, _Float16* __restrict__ Cout, int M, int N, int K)
{
    constexpr int BK = 32;
    constexpr int WM = BM / WR, WN = BN / WC;
    constexpr int MF = WM / 16, NF = WN / 16;
    constexpr int LDT = 40;
    __shared__ _Float16 Asl[BM][LDT];
    __shared__ _Float16 Bsl[BN][LDT];

    const int tid = threadIdx.x;
    const int l = tid & 63;
    const int w = tid >> 6;
    const int wr = w / WC, wc = w % WC;
    const int lr = l & 15, lh = l >> 4;
    const int bm0 = blockIdx.y * BM, bn0 = blockIdx.x * BN;

    f32x4 acc[MF][NF] = {};

    for (int k0 = 0; k0 < K; k0 += BK) {
        __syncthreads();
        for (int c = tid; c < BM * 4; c += 256) {
            int row = c >> 2, c8 = (c & 3) << 3;
            *(half8*)&Asl[row][c8] = cvt8(Aptr + (size_t)(bm0 + row) * K + k0 + c8);
        }
        for (int c = tid; c < BN * 4; c += 256) {
            int row = c >> 2, c8 = (c & 3) << 3;
            *(half8*)&Bsl[row][c8] = cvt8(Bw + (size_t)(bn0 + row) * K + k0 + c8);
        }
        __syncthreads();

        half8 a[MF], b[NF];
#pragma unroll
        for (int m = 0; m < MF; m++)
            a[m] = *(const half8*)&Asl[wr * WM + m * 16 + lr][lh * 8];
#pragma unroll
        for (int n = 0; n < NF; n++)
            b[n] = *(const half8*)&Bsl[wc * WN + n * 16 + lr][lh * 8];
#pragma unroll
        for (int m = 0; m < MF; m++)
#pragma unroll
            for (int n = 0; n < NF; n++)
                acc[m][n] = __builtin_amdgcn_mfma_f32_16x16x32_f16(a[m], b[n], acc[m][n], 0, 0, 0);
    }

#pragma unroll
    for (int m = 0; m < MF; m++)
#pragma unroll
        for (int n = 0; n < NF; n++) {
            int row0 = bm0 + wr * WM + m * 16 + lh * 4;
            int col = bn0 + wc * WN + n * 16 + lr;
            float bv = bias[col];
#pragma unroll
            for (int j = 0; j < 4; j++) {
                float val = acc[m][n][j] + bv;
                int row = row0 + j;
                int bi = row >> 11, t = row & 2047;
                Cout[(((size_t)(bi * 64 + col)) << 11) + t] = (_Float16)val;
            }
        }
}

// K-fragment loader shared by stats/emit: dst[kfr][dk], 4 x 16B global loads
#define LK(dst, kt) do {                                                          \
        const _Float16* kp_ = Kb + (size_t)((kt) * 32) * 1024;                    \
        _Pragma("unroll")                                                         \
        for (int kfr_ = 0; kfr_ < 2; kfr_++)                                      \
            _Pragma("unroll")                                                     \
            for (int dk_ = 0; dk_ < 2; dk_++)                                     \
                dst[kfr_][dk_] = *(const half8*)(kp_ + (size_t)(kfr_ * 16 + lr) * 1024 \
                                                 + ch + dk_ * 32 + lh * 8);       \
    } while (0)

// ---- stats: full-K softmax denominators. 1 head/wave, 32 q-rows, no LDS,
// no barriers, register ping-pong K prefetch. Grid 512 = 4b x 2hg x 64 qt.
__global__ __launch_bounds__(512, 4)
void stats_kernel(const _Float16* __restrict__ Qh, const _Float16* __restrict__ Kh,
                  float* __restrict__ slp)
{
    const int blk = blockIdx.x;
    const int b = blk & 3;
    const int hg = (blk >> 2) & 1;
    const int q0 = (blk >> 3) << 5;
    const int tid = threadIdx.x;
    const int l = tid & 63, w = tid >> 6;
    const int lr = l & 15, lh = l >> 4;
    const int ch = (hg * 8 + w) * 64;

    const size_t base = (size_t)b * 2048 * 1024;
    const _Float16* Qb = Qh + base;
    const _Float16* Kb = Kh + base;

    half8 qf[2][2];
#pragma unroll
    for (int m = 0; m < 2; m++)
#pragma unroll
        for (int dk = 0; dk < 2; dk++)
            qf[m][dk] = *(const half8*)(Qb + (size_t)(q0 + m * 16 + lr) * 1024
                                        + ch + dk * 32 + lh * 8);

    float sl[2][4] = {};
    half8 ka[2][2], kb2[2][2];

#define SBODY(KF) do {                                                            \
        f32x4 sc[2][2] = {};                                                      \
        _Pragma("unroll")                                                         \
        for (int m = 0; m < 2; m++)                                               \
            _Pragma("unroll")                                                     \
            for (int kfr = 0; kfr < 2; kfr++)                                     \
                _Pragma("unroll")                                                 \
                for (int dk = 0; dk < 2; dk++)                                    \
                    sc[m][kfr] = __builtin_amdgcn_mfma_f32_16x16x32_f16(          \
                        qf[m][dk], KF[kfr][dk], sc[m][kfr], 0, 0, 0);             \
        _Pragma("unroll")                                                         \
        for (int m = 0; m < 2; m++)                                               \
            _Pragma("unroll")                                                     \
            for (int j = 0; j < 4; j++)                                           \
                sl[m][j] += __builtin_amdgcn_exp2f(sc[m][0][j])                   \
                          + __builtin_amdgcn_exp2f(sc[m][1][j]);                  \
    } while (0)

    LK(ka, 0);
    for (int kt = 0; kt < 64; kt += 2) {
        LK(kb2, kt + 1);
        SBODY(ka);
        LK(ka, kt + 2 < 64 ? kt + 2 : 63);
        SBODY(kb2);
    }
#undef SBODY

#pragma unroll
    for (int m = 0; m < 2; m++)
#pragma unroll
        for (int j = 0; j < 4; j++) {
            float s = sl[m][j];
#pragma unroll
            for (int d = 1; d < 16; d <<= 1)
                s += __shfl_xor(s, d, 64);
            if (lr == 0)
                slp[(size_t)(b * 16 + hg * 8 + w) * 2048 + q0 + m * 16 + lh * 4 + j] = s;
        }
}

// ---- emit v2: SWAPPED QK^T -> packed LDS. Full-K sweep, 1 head/wave, 32 q-rows.
// mfma(K, Q): lane holds q = m*16 + (l&15), kv = kfr*16 + (l>>4)*4 + j.
// -> P staging is 4 packed b64 writes (was 16 scalar u16); PV A-frag is 2
// aligned b128 reads; head-reduce reads u32 pairs. rinv is per-lane scalar.
// Grid 512 = 4b x 2hg x 64 qt = 2 blocks/CU; 1 barrier/kt.
__global__ __launch_bounds__(512, 4)
void emit_kernel(const _Float16* __restrict__ Qh, const _Float16* __restrict__ Kh,
                 const _Float16* __restrict__ VT, const float* __restrict__ slp,
                 _Float16* __restrict__ attnp, _Float16* __restrict__ Op)
{
    const int blk = blockIdx.x;
    const int b = blk & 3;
    const int hg = (blk >> 2) & 1;
    const int q0 = (blk >> 3) << 5;
    const int tid = threadIdx.x;
    const int l = tid & 63, w = tid >> 6;
    const int lr = l & 15, lh = l >> 4;
    const int ch = (hg * 8 + w) * 64;

    // rows = q (32), cols = kv (32, pitch 40 f16 = 80B: rows 16B-aligned)
    __shared__ __align__(16) _Float16 Pld[2][8][32][40];

    const size_t base = (size_t)b * 2048 * 1024;
    const _Float16* Qb = Qh + base;
    const _Float16* Kb = Kh + base;

    half8 qf[2][2];
#pragma unroll
    for (int m = 0; m < 2; m++)
#pragma unroll
        for (int dk = 0; dk < 2; dk++)
            qf[m][dk] = *(const half8*)(Qb + (size_t)(q0 + m * 16 + lr) * 1024
                                        + ch + dk * 32 + lh * 8);

    // per-lane reciprocal denominators (q = q0 + m*16 + lr)
    float rinv[2];
    {
        const float* sr = slp + (size_t)(b * 16 + hg * 8 + w) * 2048 + q0;
#pragma unroll
        for (int m = 0; m < 2; m++)
            rinv[m] = 1.0f / sr[m * 16 + lr];
    }

    f32x4 oacc[2][4] = {};
    half8 ka[2][2], kb2[2][2];

#define EBODY(KF, KT, P) do {                                                     \
        const int krow = (KT) * 32;                                               \
        f32x4 sc[2][2] = {};   /* [m][kfr]: col=q(m,lr), row=kv(kfr,lh,j) */      \
        _Pragma("unroll")                                                         \
        for (int m = 0; m < 2; m++)                                               \
            _Pragma("unroll")                                                     \
            for (int kfr = 0; kfr < 2; kfr++)                                     \
                _Pragma("unroll")                                                 \
                for (int dk = 0; dk < 2; dk++)                                    \
                    sc[m][kfr] = __builtin_amdgcn_mfma_f32_16x16x32_f16(          \
                        KF[kfr][dk], qf[m][dk], sc[m][kfr], 0, 0, 0);             \
        _Pragma("unroll")                                                         \
        for (int m = 0; m < 2; m++)                                               \
            _Pragma("unroll")                                                     \
            for (int kfr = 0; kfr < 2; kfr++) {                                   \
                half4 pk4;                                                        \
                _Pragma("unroll")                                                 \
                for (int j = 0; j < 4; j++)                                       \
                    pk4[j] = (_Float16)(__builtin_amdgcn_exp2f(sc[m][kfr][j])     \
                                        * rinv[m]);                               \
                *(half4*)&Pld[P][w][m * 16 + lr][kfr * 16 + lh * 4] = pk4;        \
            }                                                                     \
        half8 vf[4], pa[2];                                                       \
        _Pragma("unroll")                                                         \
        for (int dv = 0; dv < 4; dv++)                                            \
            vf[dv] = *(const half8*)(VT + (((size_t)(b * 64 + dv * 16 + lr)) << 11) + krow + lh * 8); \
        _Pragma("unroll")                                                         \
        for (int m = 0; m < 2; m++)                                               \
            pa[m] = *(const half8*)&Pld[P][w][m * 16 + lr][lh * 8];               \
        _Pragma("unroll")                                                         \
        for (int m = 0; m < 2; m++)                                               \
            _Pragma("unroll")                                                     \
            for (int dv = 0; dv < 4; dv++)                                        \
                oacc[m][dv] = __builtin_amdgcn_mfma_f32_16x16x32_f16(             \
                    pa[m], vf[dv], oacc[m][dv], 0, 0, 0);                         \
        __syncthreads();                                                          \
        {                                                                         \
            int r = tid >> 4, c2 = (tid & 15) * 2;                                \
            float s0 = 0.f, s1 = 0.f;                                             \
            _Pragma("unroll")                                                     \
            for (int ww = 0; ww < 8; ww++) {                                      \
                union { uint32_t u; _Float16 h[2]; } pv;                          \
                pv.u = *(const uint32_t*)&Pld[P][ww][r][c2];                      \
                s0 += (float)pv.h[0]; s1 += (float)pv.h[1];                       \
            }                                                                     \
            union { _Float16 h[2]; uint32_t u; } pk;                              \
            pk.h[0] = (_Float16)s0; pk.h[1] = (_Float16)s1;                       \
            __builtin_nontemporal_store(pk.u, (uint32_t*)(attnp                   \
                + (size_t)hg * 16777216 + (((size_t)(b * 2048 + q0 + r)) << 11)   \
                + krow + c2));                                                    \
        }                                                                         \
    } while (0)

    LK(ka, 0);
    for (int i = 0; i < 64; i += 2) {
        LK(kb2, i + 1);
        EBODY(ka, i, 0);
        LK(ka, i + 2 < 64 ? i + 2 : 63);
        EBODY(kb2, i + 1, 1);
    }
#undef EBODY

    // O write: D col = dv*16+lr, D row = q = m*16 + lh*4 + j (unchanged indexing)
    _Float16* op = Op + base;
#pragma unroll
    for (int m = 0; m < 2; m++)
#pragma unroll
        for (int dv = 0; dv < 4; dv++)
#pragma unroll
            for (int j = 0; j < 4; j++) {
                int row = q0 + m * 16 + lh * 4 + j;
                int col = ch + dv * 16 + lr;
                op[(size_t)row * 1024 + col] = (_Float16)oacc[m][dv][j];
            }
}

extern "C" void kernel_launch(void* const* d_in, const int* in_sizes, int n_in,
                              void* d_out, int out_size, void* d_ws, size_t ws_size,
                              hipStream_t stream)
{
    const float* q  = (const float*)d_in[0];
    const float* k  = (const float*)d_in[1];
    const float* v  = (const float*)d_in[2];
    const float* Wq = (const float*)d_in[3];
    const float* bq = (const float*)d_in[4];
    const float* Wk = (const float*)d_in[5];
    const float* bk = (const float*)d_in[6];
    const float* Wv = (const float*)d_in[7];
    const float* bv = (const float*)d_in[8];
    const float* Wo = (const float*)d_in[9];
    const float* bo = (const float*)d_in[10];

    float* y = (float*)d_out;
    float* attn_mean = y + (size_t)4 * 2048 * 1024;

    uint8_t* ws = (uint8_t*)d_ws;
    _Float16* Qh  = (_Float16*)(ws);                         // 16 MB @ 0
    _Float16* Kh  = (_Float16*)(ws + 16777216);              // 16 MB
    _Float16* VT  = (_Float16*)(ws + 33554432);              // 1 MB
    _Float16* Wqc = (_Float16*)(ws + 34603008);              // 2 MB (dead after Q-proj -> slp)
    _Float16* Wkc = (_Float16*)(ws + 36700160);              // 2 MB
    _Float16* Woc = (_Float16*)(ws + 38797312);              // 2 MB
    _Float16* qc  = (_Float16*)(ws + 40894464);              // 16 MB (becomes Op)
    _Float16* kc  = (_Float16*)(ws + 57671680);              // 16 MB
    _Float16* Op  = qc;
    _Float16* attnp = (_Float16*)(ws + 74448896);            // 64 MB (2 hg partials)
    float*    slp = (float*)(ws + 34603008);                 // 512 KB over dead Wqc

    const float QS = 0.125f * 1.44269504088896340736f;

    cvt2_kernel<<<dim3(2048), dim3(256), 0, stream>>>(q, qc, k, kc, 1048576);
    cvt3_kernel<<<dim3(512),  dim3(256), 0, stream>>>(Wq, Wqc, Wk, Wkc, Wo, Woc, 131072);

    gemm16<true><<<dim3(64, 8), dim3(256), 0, stream>>>(qc, Wqc, bq, QS, Qh, 8192, 1024, 1024);
    gemm16<true><<<dim3(64, 8), dim3(256), 0, stream>>>(kc, Wkc, bk, 1.0f, Kh, 8192, 1024, 1024);
    gemm_vp<128, 64, 4, 1><<<dim3(1, 64), dim3(256), 0, stream>>>(v, Wv, bv, VT, 8192, 64, 1024);

    stats_kernel<<<dim3(512), dim3(512), 0, stream>>>(Qh, Kh, slp);
    emit_kernel<<<dim3(512), dim3(512), 0, stream>>>(Qh, Kh, VT, slp, attnp, Op);

    combine_kernel<<<dim3(2048), dim3(256), 0, stream>>>(
        attnp, attnp + (size_t)16777216, attn_mean, 2097152);

    gemm16<false><<<dim3(64, 8), dim3(256), 0, stream>>>(Op, Woc, bo, 1.0f, y, 8192, 1024, 1024);
}